// Round 1
// baseline (1829.691 us; speedup 1.0000x reference)
//
#include <hip/hip_runtime.h>
#include <math.h>

#define IN_DIM 1433
#define HID 64
#define NCLS 7

// ---------------- edge-index dtype detect ----------------
// If stored as int64 (little-endian, values < 2^31), every odd 32-bit word of
// the first row is 0. If int32, those words are random src values -> nonzero.
__global__ void detect64_kernel(const int* __restrict__ ei, int* flag, int E) {
    int i = blockIdx.x * blockDim.x + threadIdx.x;   // sample 16384 entries
    if (i < 16384 && i < E) {
        if (ei[2 * i + 1] != 0) atomicOr(flag, 1);   // flag=1 -> int32 storage
    }
}

__device__ __forceinline__ int get_src(const int* ei, int e, int E, int is32) {
    return is32 ? ei[e] : ei[2 * e];
}
__device__ __forceinline__ int get_dst(const int* ei, int e, int E, int is32) {
    return is32 ? ei[E + e] : ei[2 * E + 2 * e];
}

// ---------------- degree / norm ----------------
__global__ void count_deg_kernel(const int* __restrict__ ei, const int* __restrict__ flagp,
                                 int* __restrict__ cnt, int E) {
    int e = blockIdx.x * blockDim.x + threadIdx.x;
    if (e >= E) return;
    int is32 = *flagp;
    int d = get_dst(ei, e, E, is32);
    atomicAdd(&cnt[d], 1);
}

__global__ void dinv_kernel(const int* __restrict__ cnt, float* __restrict__ dinv, int n) {
    int i = blockIdx.x * blockDim.x + threadIdx.x;
    if (i < n) dinv[i] = rsqrtf((float)(cnt[i] + 1));   // +1: self loop, deg>=1 always
}

// ---------------- GEMM1: out[N,64] = x[N,1433] @ W[1433,64] ----------------
#define BM 128
#define BN 64
#define BKK 32

__global__ __launch_bounds__(256) void gemm1_kernel(const float* __restrict__ x,
                                                    const float* __restrict__ W,
                                                    float* __restrict__ out, int N) {
    __shared__ float As[BKK][BM + 4];   // +4 pad: keeps 16B alignment, breaks conflicts
    __shared__ float Bs[BKK][BN];
    const int tid = threadIdx.x;
    const int blockRow = blockIdx.x * BM;
    const int tr = tid >> 4;    // 0..15 -> rows tr*8..tr*8+7
    const int tc = tid & 15;    // 0..15 -> cols tc*4..tc*4+3
    const int kk = tid & 31;    // A-load k within chunk
    const int rg = tid >> 5;    // 0..7 A-load row group
    const int bc = tid & 63;    // B-load col
    const int br0 = tid >> 6;   // 0..3 B-load k base

    float acc[8][4];
#pragma unroll
    for (int i = 0; i < 8; ++i)
#pragma unroll
        for (int j = 0; j < 4; ++j) acc[i][j] = 0.f;

    for (int k0 = 0; k0 < IN_DIM; k0 += BKK) {
        const int gk = k0 + kk;
        const bool kok = gk < IN_DIM;
#pragma unroll
        for (int it = 0; it < 4; ++it) {
            int row = rg * 16 + it * 4;
            int gr = blockRow + row;
            float4 v;
            v.x = (kok && (gr + 0) < N) ? x[(size_t)(gr + 0) * IN_DIM + gk] : 0.f;
            v.y = (kok && (gr + 1) < N) ? x[(size_t)(gr + 1) * IN_DIM + gk] : 0.f;
            v.z = (kok && (gr + 2) < N) ? x[(size_t)(gr + 2) * IN_DIM + gk] : 0.f;
            v.w = (kok && (gr + 3) < N) ? x[(size_t)(gr + 3) * IN_DIM + gk] : 0.f;
            *(float4*)&As[kk][row] = v;
        }
#pragma unroll
        for (int i = 0; i < 8; ++i) {
            int r = br0 + i * 4;
            int gkb = k0 + r;
            Bs[r][bc] = (gkb < IN_DIM) ? W[gkb * BN + bc] : 0.f;
        }
        __syncthreads();
#pragma unroll
        for (int k = 0; k < BKK; ++k) {
            float4 a0 = *(const float4*)&As[k][tr * 8];
            float4 a1 = *(const float4*)&As[k][tr * 8 + 4];
            float4 bv = *(const float4*)&Bs[k][tc * 4];
            float av[8] = {a0.x, a0.y, a0.z, a0.w, a1.x, a1.y, a1.z, a1.w};
            float bw[4] = {bv.x, bv.y, bv.z, bv.w};
#pragma unroll
            for (int i = 0; i < 8; ++i)
#pragma unroll
                for (int j = 0; j < 4; ++j) acc[i][j] = fmaf(av[i], bw[j], acc[i][j]);
        }
        __syncthreads();
    }
#pragma unroll
    for (int i = 0; i < 8; ++i) {
        int gr = blockRow + tr * 8 + i;
        if (gr < N) {
            float4 v = make_float4(acc[i][0], acc[i][1], acc[i][2], acc[i][3]);
            *(float4*)&out[(size_t)gr * HID + tc * 4] = v;
        }
    }
}

// ---------------- scatter: agg[dst,f] += h[src,f] * dinv[src]*dinv[dst] ----------------
__global__ __launch_bounds__(256) void scatter_kernel(const int* __restrict__ ei,
                                                      const int* __restrict__ flagp,
                                                      const float* __restrict__ dinv,
                                                      const float* __restrict__ h,
                                                      float* __restrict__ agg, int E) {
    long long idx = (long long)blockIdx.x * blockDim.x + threadIdx.x;
    int e = (int)(idx >> 6);
    int f = (int)(idx & 63);
    if (e >= E) return;
    int is32 = *flagp;
    int s = get_src(ei, e, E, is32);
    int d = get_dst(ei, e, E, is32);
    float norm = dinv[s] * dinv[d];
    atomicAdd(&agg[(size_t)d * HID + f], h[(size_t)s * HID + f] * norm);
}

// ---------------- finalize: agg = relu(agg + t*dinv^2 + b) (self loop + bias + relu) ----
__global__ void finalize_kernel(float* __restrict__ agg, const float* __restrict__ t,
                                const float* __restrict__ dinv, const float* __restrict__ b,
                                int n64) {
    int i = blockIdx.x * blockDim.x + threadIdx.x;
    if (i >= n64) return;
    int node = i >> 6, f = i & 63;
    float di = dinv[node];
    float v = agg[i] + t[i] * di * di + b[f];
    agg[i] = v > 0.f ? v : 0.f;
}

// ---------------- GEMM2: out[N,64] = h[N,64] @ W[64,64] ----------------
__global__ __launch_bounds__(256) void gemm2_kernel(const float* __restrict__ h,
                                                    const float* __restrict__ W,
                                                    float* __restrict__ out, int n64) {
    __shared__ float Ws[HID * HID];
    for (int i = threadIdx.x; i < HID * HID; i += 256) Ws[i] = W[i];
    __syncthreads();
    int idx = blockIdx.x * blockDim.x + threadIdx.x;
    if (idx >= n64) return;
    int node = idx >> 6, c = idx & 63;
    const float* hrow = h + (size_t)node * HID;
    float acc = 0.f;
#pragma unroll 8
    for (int k = 0; k < HID; ++k) acc = fmaf(hrow[k], Ws[k * HID + c], acc);
    out[idx] = acc;
}

// ---------------- output head: logits = h2 @ Wout + bout; softmax ----------------
__global__ void out_kernel(const float* __restrict__ h2, const float* __restrict__ Wout,
                           const float* __restrict__ bout, float* __restrict__ out, int N) {
    int node = blockIdx.x * blockDim.x + threadIdx.x;
    if (node >= N) return;
    float hv[HID];
    const float4* hp = (const float4*)(h2 + (size_t)node * HID);
#pragma unroll
    for (int i = 0; i < HID / 4; ++i) {
        float4 v = hp[i];
        hv[i * 4 + 0] = v.x; hv[i * 4 + 1] = v.y; hv[i * 4 + 2] = v.z; hv[i * 4 + 3] = v.w;
    }
    float lg[NCLS];
#pragma unroll
    for (int j = 0; j < NCLS; ++j) lg[j] = bout[j];
#pragma unroll
    for (int k = 0; k < HID; ++k)
#pragma unroll
        for (int j = 0; j < NCLS; ++j) lg[j] = fmaf(hv[k], Wout[k * NCLS + j], lg[j]);
    float m = lg[0];
#pragma unroll
    for (int j = 1; j < NCLS; ++j) m = fmaxf(m, lg[j]);
    float s = 0.f;
#pragma unroll
    for (int j = 0; j < NCLS; ++j) { lg[j] = expf(lg[j] - m); s += lg[j]; }
    float inv = 1.f / s;
#pragma unroll
    for (int j = 0; j < NCLS; ++j) out[(size_t)node * NCLS + j] = lg[j] * inv;
}

// ---------------- launch ----------------
extern "C" void kernel_launch(void* const* d_in, const int* in_sizes, int n_in,
                              void* d_out, int out_size, void* d_ws, size_t ws_size,
                              hipStream_t stream) {
    const float* x    = (const float*)d_in[0];
    const int*   ei   = (const int*)d_in[1];
    const float* W1   = (const float*)d_in[2];
    const float* b1   = (const float*)d_in[3];
    const float* W2   = (const float*)d_in[4];
    const float* b2   = (const float*)d_in[5];
    const float* Wout = (const float*)d_in[6];
    const float* bout = (const float*)d_in[7];
    float* out = (float*)d_out;

    const int N = in_sizes[0] / IN_DIM;   // 100000
    const int E = in_sizes[1] / 2;        // 1600000
    const int n64 = N * HID;              // 6.4M

    char* ws = (char*)d_ws;
    int*   cnt  = (int*)(ws + 0);                 // N ints
    float* dinv = (float*)(ws + 409600);          // N floats
    float* bufA = (float*)(ws + 819200);          // N*64 (gemm out)
    float* bufB = (float*)(ws + 26419200);        // N*64 (agg1 -> h1)
    float* bufC = (float*)(ws + 52019200);        // N*64 (agg2 -> h2)
    int*   flag = (int*)(ws + 77619200);

    hipMemsetAsync(cnt, 0, (size_t)N * sizeof(int), stream);
    hipMemsetAsync(flag, 0, sizeof(int), stream);
    detect64_kernel<<<64, 256, 0, stream>>>(ei, flag, E);
    count_deg_kernel<<<(E + 255) / 256, 256, 0, stream>>>(ei, flag, cnt, E);
    dinv_kernel<<<(N + 255) / 256, 256, 0, stream>>>(cnt, dinv, N);

    // layer 1
    gemm1_kernel<<<(N + BM - 1) / BM, 256, 0, stream>>>(x, W1, bufA, N);
    hipMemsetAsync(bufB, 0, (size_t)n64 * sizeof(float), stream);
    {
        long long tot = (long long)E * HID;
        int grid = (int)((tot + 255) / 256);
        scatter_kernel<<<grid, 256, 0, stream>>>(ei, flag, dinv, bufA, bufB, E);
    }
    finalize_kernel<<<(n64 + 255) / 256, 256, 0, stream>>>(bufB, bufA, dinv, b1, n64);

    // layer 2
    gemm2_kernel<<<(n64 + 255) / 256, 256, 0, stream>>>(bufB, W2, bufA, n64);
    hipMemsetAsync(bufC, 0, (size_t)n64 * sizeof(float), stream);
    {
        long long tot = (long long)E * HID;
        int grid = (int)((tot + 255) / 256);
        scatter_kernel<<<grid, 256, 0, stream>>>(ei, flag, dinv, bufA, bufC, E);
    }
    finalize_kernel<<<(n64 + 255) / 256, 256, 0, stream>>>(bufC, bufA, dinv, b2, n64);

    // output head
    out_kernel<<<(N + 255) / 256, 256, 0, stream>>>(bufC, Wout, bout, out, N);
}

// Round 2
// 1336.583 us; speedup vs baseline: 1.3689x; 1.3689x over previous
//
#include <hip/hip_runtime.h>
#include <math.h>

#define IN_DIM 1433
#define HID 64
#define NCLS 7

// ---------------- edge-index dtype detect ----------------
// int64 storage (values < 2^31) -> every odd 32-bit word of row 0 is zero.
__global__ void detect64_kernel(const int* __restrict__ ei, int* flag, int E) {
    int i = blockIdx.x * blockDim.x + threadIdx.x;
    if (i < 16384 && i < E) {
        if (ei[2 * i + 1] != 0) atomicOr(flag, 1);   // flag=1 -> int32 storage
    }
}

__device__ __forceinline__ int get_src(const int* ei, int e, int E, int is32) {
    return is32 ? ei[e] : ei[2 * e];
}
__device__ __forceinline__ int get_dst(const int* ei, int e, int E, int is32) {
    return is32 ? ei[E + e] : ei[2 * E + 2 * e];
}

// ---------------- degree ----------------
__global__ void count_deg_kernel(const int* __restrict__ ei, const int* __restrict__ flagp,
                                 int* __restrict__ cnt, int E) {
    int e = blockIdx.x * blockDim.x + threadIdx.x;
    if (e >= E) return;
    int is32 = *flagp;
    atomicAdd(&cnt[get_dst(ei, e, E, is32)], 1);
}

__global__ void dinv_kernel(const int* __restrict__ cnt, float* __restrict__ dinv, int n) {
    int i = blockIdx.x * blockDim.x + threadIdx.x;
    if (i < n) dinv[i] = rsqrtf((float)(cnt[i] + 1));   // +1 self loop
}

// ---------------- exclusive scan (1024 elems / block) ----------------
__global__ __launch_bounds__(256) void scan_local(const int* __restrict__ in,
                                                  int* __restrict__ out,
                                                  int* __restrict__ bsum, int N) {
    int t = threadIdx.x;
    int base = blockIdx.x * 1024 + t * 4;
    int v0 = (base + 0) < N ? in[base + 0] : 0;
    int v1 = (base + 1) < N ? in[base + 1] : 0;
    int v2 = (base + 2) < N ? in[base + 2] : 0;
    int v3 = (base + 3) < N ? in[base + 3] : 0;
    int sum = v0 + v1 + v2 + v3;
    int lane = t & 63, w = t >> 6;
    int x = sum;
#pragma unroll
    for (int off = 1; off < 64; off <<= 1) {
        int y = __shfl_up(x, off);
        if (lane >= off) x += y;
    }
    __shared__ int ws[4];
    if (lane == 63) ws[w] = x;
    __syncthreads();
    int woff = 0;
#pragma unroll
    for (int i = 0; i < 4; ++i) if (i < w) woff += ws[i];
    int excl = woff + x - sum;
    if ((base + 0) < N) out[base + 0] = excl;
    if ((base + 1) < N) out[base + 1] = excl + v0;
    if ((base + 2) < N) out[base + 2] = excl + v0 + v1;
    if ((base + 3) < N) out[base + 3] = excl + v0 + v1 + v2;
    if (t == 255) bsum[blockIdx.x] = woff + x;
}

__global__ void scan_bsums(int* __restrict__ bsum, int nb) {   // nb <= 128, 64 threads
    int lane = threadIdx.x;
    int i0 = 2 * lane, i1 = 2 * lane + 1;
    int a = i0 < nb ? bsum[i0] : 0;
    int b = i1 < nb ? bsum[i1] : 0;
    int sum = a + b;
    int x = sum;
#pragma unroll
    for (int off = 1; off < 64; off <<= 1) {
        int y = __shfl_up(x, off);
        if (lane >= off) x += y;
    }
    int excl = x - sum;
    if (i0 < nb) bsum[i0] = excl;
    if (i1 < nb) bsum[i1] = excl + a;
}

__global__ void scan_add(int* __restrict__ row_ptr, int* __restrict__ cursor,
                         const int* __restrict__ bsum, int N) {
    int i = blockIdx.x * blockDim.x + threadIdx.x;
    if (i >= N) return;
    int v = row_ptr[i] + bsum[i >> 10];
    row_ptr[i] = v;
    cursor[i] = v;
}

// ---------------- CSR fill: col[pos]=src, wnrm[pos]=dinv[src] ----------------
__global__ void fill_kernel(const int* __restrict__ ei, const int* __restrict__ flagp,
                            const float* __restrict__ dinv, int* __restrict__ cursor,
                            int* __restrict__ col, float* __restrict__ wnrm, int E) {
    int e = blockIdx.x * blockDim.x + threadIdx.x;
    if (e >= E) return;
    int is32 = *flagp;
    int s = get_src(ei, e, E, is32);
    int d = get_dst(ei, e, E, is32);
    int pos = atomicAdd(&cursor[d], 1);
    col[pos] = s;
    wnrm[pos] = dinv[s];
}

// ---------------- GEMM1: out[N,64] = x[N,1433] @ W[1433,64] (unchanged) --------
#define BM 128
#define BN 64
#define BKK 32

__global__ __launch_bounds__(256) void gemm1_kernel(const float* __restrict__ x,
                                                    const float* __restrict__ W,
                                                    float* __restrict__ out, int N) {
    __shared__ float As[BKK][BM + 4];
    __shared__ float Bs[BKK][BN];
    const int tid = threadIdx.x;
    const int blockRow = blockIdx.x * BM;
    const int tr = tid >> 4;
    const int tc = tid & 15;
    const int kk = tid & 31;
    const int rg = tid >> 5;
    const int bc = tid & 63;
    const int br0 = tid >> 6;

    float acc[8][4];
#pragma unroll
    for (int i = 0; i < 8; ++i)
#pragma unroll
        for (int j = 0; j < 4; ++j) acc[i][j] = 0.f;

    for (int k0 = 0; k0 < IN_DIM; k0 += BKK) {
        const int gk = k0 + kk;
        const bool kok = gk < IN_DIM;
#pragma unroll
        for (int it = 0; it < 4; ++it) {
            int row = rg * 16 + it * 4;
            int gr = blockRow + row;
            float4 v;
            v.x = (kok && (gr + 0) < N) ? x[(size_t)(gr + 0) * IN_DIM + gk] : 0.f;
            v.y = (kok && (gr + 1) < N) ? x[(size_t)(gr + 1) * IN_DIM + gk] : 0.f;
            v.z = (kok && (gr + 2) < N) ? x[(size_t)(gr + 2) * IN_DIM + gk] : 0.f;
            v.w = (kok && (gr + 3) < N) ? x[(size_t)(gr + 3) * IN_DIM + gk] : 0.f;
            *(float4*)&As[kk][row] = v;
        }
#pragma unroll
        for (int i = 0; i < 8; ++i) {
            int r = br0 + i * 4;
            int gkb = k0 + r;
            Bs[r][bc] = (gkb < IN_DIM) ? W[gkb * BN + bc] : 0.f;
        }
        __syncthreads();
#pragma unroll
        for (int k = 0; k < BKK; ++k) {
            float4 a0 = *(const float4*)&As[k][tr * 8];
            float4 a1 = *(const float4*)&As[k][tr * 8 + 4];
            float4 bv = *(const float4*)&Bs[k][tc * 4];
            float av[8] = {a0.x, a0.y, a0.z, a0.w, a1.x, a1.y, a1.z, a1.w};
            float bw[4] = {bv.x, bv.y, bv.z, bv.w};
#pragma unroll
            for (int i = 0; i < 8; ++i)
#pragma unroll
                for (int j = 0; j < 4; ++j) acc[i][j] = fmaf(av[i], bw[j], acc[i][j]);
        }
        __syncthreads();
    }
#pragma unroll
    for (int i = 0; i < 8; ++i) {
        int gr = blockRow + tr * 8 + i;
        if (gr < N) {
            float4 v = make_float4(acc[i][0], acc[i][1], acc[i][2], acc[i][3]);
            *(float4*)&out[(size_t)gr * HID + tc * 4] = v;
        }
    }
}

// ---------------- CSR aggregation: out[d] = relu(dinv[d]*(sum_e dinv[s]h[s] + dinv[d]h[d]) + b)
// wave per node; 16 lanes x 4 edge-slots; float4 gathers; no atomics, no DS ops.
__global__ __launch_bounds__(256) void agg_kernel(const int* __restrict__ row_ptr,
                                                  const int* __restrict__ cnt,
                                                  const int* __restrict__ col,
                                                  const float* __restrict__ wnrm,
                                                  const float* __restrict__ dinv,
                                                  const float* __restrict__ h,
                                                  const float* __restrict__ bias,
                                                  float* __restrict__ out, int N) {
    int node = blockIdx.x * 4 + (threadIdx.x >> 6);
    if (node >= N) return;
    int lane = threadIdx.x & 63;
    int g = lane >> 4;        // edge slot 0..3
    int q = lane & 15;        // feature quad 0..15
    int start = row_ptr[node];
    int end = start + cnt[node];

    float ax = 0.f, ay = 0.f, az = 0.f, aw = 0.f;
    for (int e0 = start; e0 < end; e0 += 8) {
        int ea = e0 + g;
        int eb = e0 + 4 + g;
        int sa = 0, sb = 0;
        float wa = 0.f, wb = 0.f;
        if (ea < end) { sa = col[ea]; wa = wnrm[ea]; }
        if (eb < end) { sb = col[eb]; wb = wnrm[eb]; }
        const float4 ha = *(const float4*)&h[(size_t)sa * HID + q * 4];
        const float4 hb = *(const float4*)&h[(size_t)sb * HID + q * 4];
        ax = fmaf(ha.x, wa, ax); ay = fmaf(ha.y, wa, ay);
        az = fmaf(ha.z, wa, az); aw = fmaf(ha.w, wa, aw);
        ax = fmaf(hb.x, wb, ax); ay = fmaf(hb.y, wb, ay);
        az = fmaf(hb.z, wb, az); aw = fmaf(hb.w, wb, aw);
    }
    // reduce the 4 edge-slot copies (lanes differing in bits 4..5)
    ax += __shfl_xor(ax, 16); ay += __shfl_xor(ay, 16);
    az += __shfl_xor(az, 16); aw += __shfl_xor(aw, 16);
    ax += __shfl_xor(ax, 32); ay += __shfl_xor(ay, 32);
    az += __shfl_xor(az, 32); aw += __shfl_xor(aw, 32);

    if (g == 0) {
        float dn = dinv[node];
        const float4 hs = *(const float4*)&h[(size_t)node * HID + q * 4];
        const float4 bq = *(const float4*)&bias[q * 4];
        float4 r;
        r.x = fmaxf(fmaf(dn, fmaf(dn, hs.x, ax), bq.x), 0.f);
        r.y = fmaxf(fmaf(dn, fmaf(dn, hs.y, ay), bq.y), 0.f);
        r.z = fmaxf(fmaf(dn, fmaf(dn, hs.z, az), bq.z), 0.f);
        r.w = fmaxf(fmaf(dn, fmaf(dn, hs.w, aw), bq.w), 0.f);
        *(float4*)&out[(size_t)node * HID + q * 4] = r;
    }
}

// ---------------- GEMM2: out[N,64] = h[N,64] @ W[64,64] ----------------
__global__ __launch_bounds__(256) void gemm2_kernel(const float* __restrict__ h,
                                                    const float* __restrict__ W,
                                                    float* __restrict__ out, int n64) {
    __shared__ float Ws[HID * HID];
    for (int i = threadIdx.x; i < HID * HID; i += 256) Ws[i] = W[i];
    __syncthreads();
    int idx = blockIdx.x * blockDim.x + threadIdx.x;
    if (idx >= n64) return;
    int node = idx >> 6, c = idx & 63;
    const float* hrow = h + (size_t)node * HID;
    float acc = 0.f;
#pragma unroll 8
    for (int k = 0; k < HID; ++k) acc = fmaf(hrow[k], Ws[k * HID + c], acc);
    out[idx] = acc;
}

// ---------------- output head ----------------
__global__ void out_kernel(const float* __restrict__ h2, const float* __restrict__ Wout,
                           const float* __restrict__ bout, float* __restrict__ out, int N) {
    int node = blockIdx.x * blockDim.x + threadIdx.x;
    if (node >= N) return;
    float hv[HID];
    const float4* hp = (const float4*)(h2 + (size_t)node * HID);
#pragma unroll
    for (int i = 0; i < HID / 4; ++i) {
        float4 v = hp[i];
        hv[i * 4 + 0] = v.x; hv[i * 4 + 1] = v.y; hv[i * 4 + 2] = v.z; hv[i * 4 + 3] = v.w;
    }
    float lg[NCLS];
#pragma unroll
    for (int j = 0; j < NCLS; ++j) lg[j] = bout[j];
#pragma unroll
    for (int k = 0; k < HID; ++k)
#pragma unroll
        for (int j = 0; j < NCLS; ++j) lg[j] = fmaf(hv[k], Wout[k * NCLS + j], lg[j]);
    float m = lg[0];
#pragma unroll
    for (int j = 1; j < NCLS; ++j) m = fmaxf(m, lg[j]);
    float s = 0.f;
#pragma unroll
    for (int j = 0; j < NCLS; ++j) { lg[j] = expf(lg[j] - m); s += lg[j]; }
    float inv = 1.f / s;
#pragma unroll
    for (int j = 0; j < NCLS; ++j) out[(size_t)node * NCLS + j] = lg[j] * inv;
}

// ---------------- launch ----------------
extern "C" void kernel_launch(void* const* d_in, const int* in_sizes, int n_in,
                              void* d_out, int out_size, void* d_ws, size_t ws_size,
                              hipStream_t stream) {
    const float* x    = (const float*)d_in[0];
    const int*   ei   = (const int*)d_in[1];
    const float* W1   = (const float*)d_in[2];
    const float* b1   = (const float*)d_in[3];
    const float* W2   = (const float*)d_in[4];
    const float* b2   = (const float*)d_in[5];
    const float* Wout = (const float*)d_in[6];
    const float* bout = (const float*)d_in[7];
    float* out = (float*)d_out;

    const int N = in_sizes[0] / IN_DIM;   // 100000
    const int E = in_sizes[1] / 2;        // 1600000
    const int n64 = N * HID;

    // workspace layout (all offsets 256B-aligned)
    char* ws = (char*)d_ws;
    size_t off = 0;
    auto take = [&](size_t bytes) { char* p = ws + off; off = (off + bytes + 255) & ~(size_t)255; return p; };
    int*   cnt     = (int*)take((size_t)N * 4);
    float* dinv    = (float*)take((size_t)N * 4);
    int*   row_ptr = (int*)take((size_t)N * 4);
    int*   cursor  = (int*)take((size_t)N * 4);
    int*   bsum    = (int*)take(512);
    int*   flag    = (int*)take(256);
    int*   col     = (int*)take((size_t)E * 4);
    float* wnrm    = (float*)take((size_t)E * 4);
    float* P0      = (float*)take((size_t)n64 * 4);
    float* P1      = (float*)take((size_t)n64 * 4);

    hipMemsetAsync(cnt, 0, (size_t)N * sizeof(int), stream);
    hipMemsetAsync(flag, 0, sizeof(int), stream);
    detect64_kernel<<<64, 256, 0, stream>>>(ei, flag, E);
    count_deg_kernel<<<(E + 255) / 256, 256, 0, stream>>>(ei, flag, cnt, E);
    dinv_kernel<<<(N + 255) / 256, 256, 0, stream>>>(cnt, dinv, N);

    // CSR build
    int nb = (N + 1023) / 1024;
    scan_local<<<nb, 256, 0, stream>>>(cnt, row_ptr, bsum, N);
    scan_bsums<<<1, 64, 0, stream>>>(bsum, nb);
    scan_add<<<(N + 255) / 256, 256, 0, stream>>>(row_ptr, cursor, bsum, N);
    fill_kernel<<<(E + 255) / 256, 256, 0, stream>>>(ei, flag, dinv, cursor, col, wnrm, E);

    // layer 1
    gemm1_kernel<<<(N + BM - 1) / BM, 256, 0, stream>>>(x, W1, P0, N);
    agg_kernel<<<(N + 3) / 4, 256, 0, stream>>>(row_ptr, cnt, col, wnrm, dinv, P0, b1, P1, N);

    // layer 2
    gemm2_kernel<<<(n64 + 255) / 256, 256, 0, stream>>>(P1, W2, P0, n64);
    agg_kernel<<<(N + 3) / 4, 256, 0, stream>>>(row_ptr, cnt, col, wnrm, dinv, P0, b2, P1, N);

    // output head
    out_kernel<<<(N + 255) / 256, 256, 0, stream>>>(P1, Wout, bout, out, N);
}

// Round 3
// 1253.229 us; speedup vs baseline: 1.4600x; 1.0665x over previous
//
#include <hip/hip_runtime.h>
#include <math.h>

#define IN_DIM 1433
#define KPAD1 1440
#define HID 64
#define NCLS 7

typedef __attribute__((ext_vector_type(8))) short short8;
typedef __attribute__((ext_vector_type(4))) float f32x4;

// ---------------- edge-index dtype detect ----------------
__global__ void detect64_kernel(const int* __restrict__ ei, int* flag, int E) {
    int i = blockIdx.x * blockDim.x + threadIdx.x;
    if (i < 16384 && i < E) {
        if (ei[2 * i + 1] != 0) atomicOr(flag, 1);   // flag=1 -> int32 storage
    }
}

__device__ __forceinline__ int get_src(const int* ei, int e, int E, int is32) {
    return is32 ? ei[e] : ei[2 * e];
}
__device__ __forceinline__ int get_dst(const int* ei, int e, int E, int is32) {
    return is32 ? ei[E + e] : ei[2 * E + 2 * e];
}

// ---------------- degree ----------------
__global__ void count_deg_kernel(const int* __restrict__ ei, const int* __restrict__ flagp,
                                 int* __restrict__ cnt, int E) {
    int e = blockIdx.x * blockDim.x + threadIdx.x;
    if (e >= E) return;
    int is32 = *flagp;
    atomicAdd(&cnt[get_dst(ei, e, E, is32)], 1);
}

__global__ void dinv_kernel(const int* __restrict__ cnt, float* __restrict__ dinv, int n) {
    int i = blockIdx.x * blockDim.x + threadIdx.x;
    if (i < n) dinv[i] = rsqrtf((float)(cnt[i] + 1));   // +1 self loop
}

// ---------------- exclusive scan (1024 elems / block) ----------------
__global__ __launch_bounds__(256) void scan_local(const int* __restrict__ in,
                                                  int* __restrict__ out,
                                                  int* __restrict__ bsum, int N) {
    int t = threadIdx.x;
    int base = blockIdx.x * 1024 + t * 4;
    int v0 = (base + 0) < N ? in[base + 0] : 0;
    int v1 = (base + 1) < N ? in[base + 1] : 0;
    int v2 = (base + 2) < N ? in[base + 2] : 0;
    int v3 = (base + 3) < N ? in[base + 3] : 0;
    int sum = v0 + v1 + v2 + v3;
    int lane = t & 63, w = t >> 6;
    int x = sum;
#pragma unroll
    for (int off = 1; off < 64; off <<= 1) {
        int y = __shfl_up(x, off);
        if (lane >= off) x += y;
    }
    __shared__ int ws[4];
    if (lane == 63) ws[w] = x;
    __syncthreads();
    int woff = 0;
#pragma unroll
    for (int i = 0; i < 4; ++i) if (i < w) woff += ws[i];
    int excl = woff + x - sum;
    if ((base + 0) < N) out[base + 0] = excl;
    if ((base + 1) < N) out[base + 1] = excl + v0;
    if ((base + 2) < N) out[base + 2] = excl + v0 + v1;
    if ((base + 3) < N) out[base + 3] = excl + v0 + v1 + v2;
    if (t == 255) bsum[blockIdx.x] = woff + x;
}

__global__ void scan_bsums(int* __restrict__ bsum, int nb) {   // nb <= 128, 64 threads
    int lane = threadIdx.x;
    int i0 = 2 * lane, i1 = 2 * lane + 1;
    int a = i0 < nb ? bsum[i0] : 0;
    int b = i1 < nb ? bsum[i1] : 0;
    int sum = a + b;
    int x = sum;
#pragma unroll
    for (int off = 1; off < 64; off <<= 1) {
        int y = __shfl_up(x, off);
        if (lane >= off) x += y;
    }
    int excl = x - sum;
    if (i0 < nb) bsum[i0] = excl;
    if (i1 < nb) bsum[i1] = excl + a;
}

__global__ void scan_add(int* __restrict__ row_ptr, int* __restrict__ cursor,
                         const int* __restrict__ bsum, int N) {
    int i = blockIdx.x * blockDim.x + threadIdx.x;
    if (i >= N) return;
    int v = row_ptr[i] + bsum[i >> 10];
    row_ptr[i] = v;
    cursor[i] = v;
}

// ---------------- CSR fill ----------------
__global__ void fill_kernel(const int* __restrict__ ei, const int* __restrict__ flagp,
                            const float* __restrict__ dinv, int* __restrict__ cursor,
                            int* __restrict__ col, float* __restrict__ wnrm, int E) {
    int e = blockIdx.x * blockDim.x + threadIdx.x;
    if (e >= E) return;
    int is32 = *flagp;
    int s = get_src(ei, e, E, is32);
    int d = get_dst(ei, e, E, is32);
    int pos = atomicAdd(&cursor[d], 1);
    col[pos] = s;
    wnrm[pos] = dinv[s];
}

// ---------------- W preconvert: Wt_hi/lo[col][kpad] bf16, transposed+split ------
__global__ void convw_kernel(const float* __restrict__ W, short* __restrict__ Bh,
                             short* __restrict__ Bl, int K, int KP, int ncol) {
    int idx = blockIdx.x * blockDim.x + threadIdx.x;
    if (idx >= ncol * KP) return;
    int colc = idx / KP, k = idx - colc * KP;
    float v = (k < K) ? W[(size_t)k * ncol + colc] : 0.f;
    unsigned u = __float_as_uint(v);
    float hif = __uint_as_float(u & 0xFFFF0000u);
    float lof = v - hif;
    Bh[idx] = (short)(u >> 16);
    Bl[idx] = (short)(__float_as_uint(lof) >> 16);
}

// ---------------- MFMA GEMM: out[N,64] = x[N,K] @ W[K,64] via bf16 3-split -------
// No LDS: A frags global->reg->split; B frags from pre-split Wt[col][KP].
// 16x16x32 layouts (HW-verified): A: m=lane&15, k=(lane>>4)*8+j
//                                 B: n=lane&15, k=(lane>>4)*8+j
//                               C/D: col=lane&15, row=(lane>>4)*4+reg
template<int K, int KP>
__global__ __launch_bounds__(256) void gemm_mfma(const float* __restrict__ x,
                                                 const short* __restrict__ Bh,
                                                 const short* __restrict__ Bl,
                                                 float* __restrict__ out, int N) {
    const int tid = threadIdx.x;
    const int w = tid >> 6, lane = tid & 63;
    const int q = lane >> 4, m16 = lane & 15;
    const int blockRow = blockIdx.x * 128;

    f32x4 acc[2][4];
#pragma unroll
    for (int i = 0; i < 2; ++i)
#pragma unroll
        for (int c = 0; c < 4; ++c) acc[i][c] = (f32x4)(0.f);

    const int row0 = blockRow + 16 * (2 * w + 0) + m16;
    const int row1 = blockRow + 16 * (2 * w + 1) + m16;
    const float* a0p = x + (size_t)min(row0, N - 1) * K;
    const float* a1p = x + (size_t)min(row1, N - 1) * K;

    const int nchunk = KP / 32;
    for (int c = 0; c < nchunk; ++c) {
        const int k0 = c * 32 + q * 8;
        float av0[8], av1[8];
        if (k0 + 8 <= K) {
            __builtin_memcpy(&av0[0], a0p + k0, 16);
            __builtin_memcpy(&av0[4], a0p + k0 + 4, 16);
            __builtin_memcpy(&av1[0], a1p + k0, 16);
            __builtin_memcpy(&av1[4], a1p + k0 + 4, 16);
        } else {
#pragma unroll
            for (int j = 0; j < 8; ++j) {
                int k = k0 + j;
                av0[j] = (k < K) ? a0p[k] : 0.f;
                av1[j] = (k < K) ? a1p[k] : 0.f;
            }
        }
        short8 ah0, al0, ah1, al1;
#pragma unroll
        for (int j = 0; j < 8; ++j) {
            unsigned u0 = __float_as_uint(av0[j]);
            float lo0 = av0[j] - __uint_as_float(u0 & 0xFFFF0000u);
            ah0[j] = (short)(u0 >> 16);
            al0[j] = (short)(__float_as_uint(lo0) >> 16);
            unsigned u1 = __float_as_uint(av1[j]);
            float lo1 = av1[j] - __uint_as_float(u1 & 0xFFFF0000u);
            ah1[j] = (short)(u1 >> 16);
            al1[j] = (short)(__float_as_uint(lo1) >> 16);
        }
        short8 bh[4], bl[4];
#pragma unroll
        for (int ct = 0; ct < 4; ++ct) {
            size_t boff = (size_t)(16 * ct + m16) * KP + k0;
            __builtin_memcpy(&bh[ct], Bh + boff, 16);
            __builtin_memcpy(&bl[ct], Bl + boff, 16);
        }
#pragma unroll
        for (int ct = 0; ct < 4; ++ct) {
            acc[0][ct] = __builtin_amdgcn_mfma_f32_16x16x32_bf16(ah0, bh[ct], acc[0][ct], 0, 0, 0);
            acc[0][ct] = __builtin_amdgcn_mfma_f32_16x16x32_bf16(ah0, bl[ct], acc[0][ct], 0, 0, 0);
            acc[0][ct] = __builtin_amdgcn_mfma_f32_16x16x32_bf16(al0, bh[ct], acc[0][ct], 0, 0, 0);
            acc[1][ct] = __builtin_amdgcn_mfma_f32_16x16x32_bf16(ah1, bh[ct], acc[1][ct], 0, 0, 0);
            acc[1][ct] = __builtin_amdgcn_mfma_f32_16x16x32_bf16(ah1, bl[ct], acc[1][ct], 0, 0, 0);
            acc[1][ct] = __builtin_amdgcn_mfma_f32_16x16x32_bf16(al1, bh[ct], acc[1][ct], 0, 0, 0);
        }
    }
#pragma unroll
    for (int i = 0; i < 2; ++i) {
        int rbase = blockRow + 16 * (2 * w + i) + q * 4;
#pragma unroll
        for (int r = 0; r < 4; ++r) {
            int row = rbase + r;
            if (row < N) {
#pragma unroll
                for (int ct = 0; ct < 4; ++ct)
                    out[(size_t)row * HID + 16 * ct + m16] = acc[i][ct][r];
            }
        }
    }
}

// ---------------- CSR aggregation (unchanged) ----------------
__global__ __launch_bounds__(256) void agg_kernel(const int* __restrict__ row_ptr,
                                                  const int* __restrict__ cnt,
                                                  const int* __restrict__ col,
                                                  const float* __restrict__ wnrm,
                                                  const float* __restrict__ dinv,
                                                  const float* __restrict__ h,
                                                  const float* __restrict__ bias,
                                                  float* __restrict__ out, int N) {
    int node = blockIdx.x * 4 + (threadIdx.x >> 6);
    if (node >= N) return;
    int lane = threadIdx.x & 63;
    int g = lane >> 4;
    int q = lane & 15;
    int start = row_ptr[node];
    int end = start + cnt[node];

    float ax = 0.f, ay = 0.f, az = 0.f, aw = 0.f;
    for (int e0 = start; e0 < end; e0 += 8) {
        int ea = e0 + g;
        int eb = e0 + 4 + g;
        int sa = 0, sb = 0;
        float wa = 0.f, wb = 0.f;
        if (ea < end) { sa = col[ea]; wa = wnrm[ea]; }
        if (eb < end) { sb = col[eb]; wb = wnrm[eb]; }
        const float4 ha = *(const float4*)&h[(size_t)sa * HID + q * 4];
        const float4 hb = *(const float4*)&h[(size_t)sb * HID + q * 4];
        ax = fmaf(ha.x, wa, ax); ay = fmaf(ha.y, wa, ay);
        az = fmaf(ha.z, wa, az); aw = fmaf(ha.w, wa, aw);
        ax = fmaf(hb.x, wb, ax); ay = fmaf(hb.y, wb, ay);
        az = fmaf(hb.z, wb, az); aw = fmaf(hb.w, wb, aw);
    }
    ax += __shfl_xor(ax, 16); ay += __shfl_xor(ay, 16);
    az += __shfl_xor(az, 16); aw += __shfl_xor(aw, 16);
    ax += __shfl_xor(ax, 32); ay += __shfl_xor(ay, 32);
    az += __shfl_xor(az, 32); aw += __shfl_xor(aw, 32);

    if (g == 0) {
        float dn = dinv[node];
        const float4 hs = *(const float4*)&h[(size_t)node * HID + q * 4];
        const float4 bq = *(const float4*)&bias[q * 4];
        float4 r;
        r.x = fmaxf(fmaf(dn, fmaf(dn, hs.x, ax), bq.x), 0.f);
        r.y = fmaxf(fmaf(dn, fmaf(dn, hs.y, ay), bq.y), 0.f);
        r.z = fmaxf(fmaf(dn, fmaf(dn, hs.z, az), bq.z), 0.f);
        r.w = fmaxf(fmaf(dn, fmaf(dn, hs.w, aw), bq.w), 0.f);
        *(float4*)&out[(size_t)node * HID + q * 4] = r;
    }
}

// ---------------- output head ----------------
__global__ void out_kernel(const float* __restrict__ h2, const float* __restrict__ Wout,
                           const float* __restrict__ bout, float* __restrict__ out, int N) {
    int node = blockIdx.x * blockDim.x + threadIdx.x;
    if (node >= N) return;
    float hv[HID];
    const float4* hp = (const float4*)(h2 + (size_t)node * HID);
#pragma unroll
    for (int i = 0; i < HID / 4; ++i) {
        float4 v = hp[i];
        hv[i * 4 + 0] = v.x; hv[i * 4 + 1] = v.y; hv[i * 4 + 2] = v.z; hv[i * 4 + 3] = v.w;
    }
    float lg[NCLS];
#pragma unroll
    for (int j = 0; j < NCLS; ++j) lg[j] = bout[j];
#pragma unroll
    for (int k = 0; k < HID; ++k)
#pragma unroll
        for (int j = 0; j < NCLS; ++j) lg[j] = fmaf(hv[k], Wout[k * NCLS + j], lg[j]);
    float m = lg[0];
#pragma unroll
    for (int j = 1; j < NCLS; ++j) m = fmaxf(m, lg[j]);
    float s = 0.f;
#pragma unroll
    for (int j = 0; j < NCLS; ++j) { lg[j] = expf(lg[j] - m); s += lg[j]; }
    float inv = 1.f / s;
#pragma unroll
    for (int j = 0; j < NCLS; ++j) out[(size_t)node * NCLS + j] = lg[j] * inv;
}

// ---------------- launch ----------------
extern "C" void kernel_launch(void* const* d_in, const int* in_sizes, int n_in,
                              void* d_out, int out_size, void* d_ws, size_t ws_size,
                              hipStream_t stream) {
    const float* x    = (const float*)d_in[0];
    const int*   ei   = (const int*)d_in[1];
    const float* W1   = (const float*)d_in[2];
    const float* b1   = (const float*)d_in[3];
    const float* W2   = (const float*)d_in[4];
    const float* b2   = (const float*)d_in[5];
    const float* Wout = (const float*)d_in[6];
    const float* bout = (const float*)d_in[7];
    float* out = (float*)d_out;

    const int N = in_sizes[0] / IN_DIM;   // 100000
    const int E = in_sizes[1] / 2;        // 1600000
    const int n64 = N * HID;

    char* ws = (char*)d_ws;
    size_t off = 0;
    auto take = [&](size_t bytes) { char* p = ws + off; off = (off + bytes + 255) & ~(size_t)255; return p; };
    int*   cnt     = (int*)take((size_t)N * 4);
    float* dinv    = (float*)take((size_t)N * 4);
    int*   row_ptr = (int*)take((size_t)N * 4);
    int*   cursor  = (int*)take((size_t)N * 4);
    int*   bsum    = (int*)take(512);
    int*   flag    = (int*)take(256);
    int*   col     = (int*)take((size_t)E * 4);
    float* wnrm    = (float*)take((size_t)E * 4);
    float* P0      = (float*)take((size_t)n64 * 4);
    float* P1      = (float*)take((size_t)n64 * 4);
    short* W1h     = (short*)take((size_t)HID * KPAD1 * 2);
    short* W1l     = (short*)take((size_t)HID * KPAD1 * 2);
    short* W2h     = (short*)take((size_t)HID * HID * 2);
    short* W2l     = (short*)take((size_t)HID * HID * 2);

    hipMemsetAsync(cnt, 0, (size_t)N * sizeof(int), stream);
    hipMemsetAsync(flag, 0, sizeof(int), stream);
    detect64_kernel<<<64, 256, 0, stream>>>(ei, flag, E);
    count_deg_kernel<<<(E + 255) / 256, 256, 0, stream>>>(ei, flag, cnt, E);
    dinv_kernel<<<(N + 255) / 256, 256, 0, stream>>>(cnt, dinv, N);

    // CSR build
    int nb = (N + 1023) / 1024;
    scan_local<<<nb, 256, 0, stream>>>(cnt, row_ptr, bsum, N);
    scan_bsums<<<1, 64, 0, stream>>>(bsum, nb);
    scan_add<<<(N + 255) / 256, 256, 0, stream>>>(row_ptr, cursor, bsum, N);
    fill_kernel<<<(E + 255) / 256, 256, 0, stream>>>(ei, flag, dinv, cursor, col, wnrm, E);

    // W preconvert (transposed + bf16 hi/lo split)
    convw_kernel<<<(HID * KPAD1 + 255) / 256, 256, 0, stream>>>(W1, W1h, W1l, IN_DIM, KPAD1, HID);
    convw_kernel<<<(HID * HID + 255) / 256, 256, 0, stream>>>(W2, W2h, W2l, HID, HID, HID);

    const int gblocks = (N + 127) / 128;
    // layer 1
    gemm_mfma<IN_DIM, KPAD1><<<gblocks, 256, 0, stream>>>(x, W1h, W1l, P0, N);
    agg_kernel<<<(N + 3) / 4, 256, 0, stream>>>(row_ptr, cnt, col, wnrm, dinv, P0, b1, P1, N);

    // layer 2
    gemm_mfma<HID, HID><<<gblocks, 256, 0, stream>>>(P1, W2h, W2l, P0, N);
    agg_kernel<<<(N + 3) / 4, 256, 0, stream>>>(row_ptr, cnt, col, wnrm, dinv, P0, b2, P1, N);

    // output head
    out_kernel<<<(N + 255) / 256, 256, 0, stream>>>(P1, Wout, bout, out, N);
}